// Round 1
// baseline (177.903 us; speedup 1.0000x reference)
//
#include <hip/hip_runtime.h>

// GAE backward scan. B rows (independent), T=2048 timesteps each.
// One 256-thread block per row; thread j owns elements [8j, 8j+8).
// Affine-recurrence parallel scan: intra-chunk serial (registers) +
// inter-chunk Hillis-Steele composition scan (LDS, 8 steps).

constexpr float GAMMA = 0.99f;
constexpr float LMBDA = 0.95f;
constexpr int   T     = 2048;
constexpr int   TPB   = 256;
constexpr int   E     = T / TPB;  // 8 elements per thread

__global__ __launch_bounds__(TPB) void gae_kernel(
    const float* __restrict__ reward,
    const int*   __restrict__ term,
    const float* __restrict__ value,
    const float* __restrict__ next_value,
    float* __restrict__ adv_out,
    float* __restrict__ ret_out)
{
    const int b = blockIdx.x;
    const int j = threadIdx.x;
    const size_t base = (size_t)b * T + (size_t)j * E;

    // Coalesced vector loads: each thread 32 contiguous bytes per array.
    float4 rA = ((const float4*)(reward     + base))[0];
    float4 rB = ((const float4*)(reward     + base))[1];
    int4   tA = ((const int4*  )(term       + base))[0];
    int4   tB = ((const int4*  )(term       + base))[1];
    float4 vA = ((const float4*)(value      + base))[0];
    float4 vB = ((const float4*)(value      + base))[1];
    float4 nA = ((const float4*)(next_value + base))[0];
    float4 nB = ((const float4*)(next_value + base))[1];

    float r [E] = {rA.x, rA.y, rA.z, rA.w, rB.x, rB.y, rB.z, rB.w};
    float nd[E] = {1.f - (float)tA.x, 1.f - (float)tA.y, 1.f - (float)tA.z, 1.f - (float)tA.w,
                   1.f - (float)tB.x, 1.f - (float)tB.y, 1.f - (float)tB.z, 1.f - (float)tB.w};
    float v [E] = {vA.x, vA.y, vA.z, vA.w, vB.x, vB.y, vB.z, vB.w};
    float nv[E] = {nA.x, nA.y, nA.z, nA.w, nB.x, nB.y, nB.z, nB.w};

    // Intra-chunk backward scan with zero incoming carry.
    // loc[t]: local gae; P[t]: product of c over [t .. E-1] (carry transmittance).
    float loc[E], P[E];
    float g = 0.f, p = 1.f;
    #pragma unroll
    for (int t = E - 1; t >= 0; --t) {
        float c     = (GAMMA * LMBDA) * nd[t];
        float delta = fmaf(GAMMA * nv[t], nd[t], r[t]) - v[t];
        g = fmaf(c, g, delta);
        p *= c;
        loc[t] = g;
        P[t]   = p;
    }

    // Chunk affine map: carry_out = A + B * carry_in, A = loc[0], B = P[0].
    // Backward inclusive scan of composition F_j = f_j ∘ f_{j+1} ∘ ... ∘ f_{TPB-1}.
    __shared__ float sA[TPB], sB[TPB];
    sA[j] = loc[0];
    sB[j] = P[0];
    __syncthreads();
    #pragma unroll
    for (int off = 1; off < TPB; off <<= 1) {
        float a1 = sA[j], b1 = sB[j];
        float a2 = 0.f, b2 = 0.f;
        const int k = j + off;
        const bool valid = (k < TPB);
        if (valid) { a2 = sA[k]; b2 = sB[k]; }
        __syncthreads();
        if (valid) {
            sA[j] = fmaf(b1, a2, a1);  // (f_own ∘ f_right)(x) = a1 + b1*(a2 + b2*x)
            sB[j] = b1 * b2;
        }
        __syncthreads();
    }
    // Incoming carry for chunk j is F_{j+1}(0); rightmost chunk gets 0.
    const float gin = (j + 1 < TPB) ? sA[j + 1] : 0.f;

    float adv[E], ret[E];
    #pragma unroll
    for (int t = 0; t < E; ++t) {
        adv[t] = fmaf(P[t], gin, loc[t]);
        ret[t] = adv[t] + v[t];
    }

    ((float4*)(adv_out + base))[0] = make_float4(adv[0], adv[1], adv[2], adv[3]);
    ((float4*)(adv_out + base))[1] = make_float4(adv[4], adv[5], adv[6], adv[7]);
    ((float4*)(ret_out + base))[0] = make_float4(ret[0], ret[1], ret[2], ret[3]);
    ((float4*)(ret_out + base))[1] = make_float4(ret[4], ret[5], ret[6], ret[7]);
}

extern "C" void kernel_launch(void* const* d_in, const int* in_sizes, int n_in,
                              void* d_out, int out_size, void* d_ws, size_t ws_size,
                              hipStream_t stream) {
    const float* reward     = (const float*)d_in[0];
    const int*   term       = (const int*  )d_in[1];
    const float* value      = (const float*)d_in[2];
    const float* next_value = (const float*)d_in[3];

    const int BT = in_sizes[0];     // B * T
    const int B  = BT / T;          // T = 2048 per setup_inputs

    float* adv = (float*)d_out;     // outputs concatenated: advantages, returns
    float* ret = adv + BT;

    gae_kernel<<<B, TPB, 0, stream>>>(reward, term, value, next_value, adv, ret);
}